// Round 2
// baseline (10099.091 us; speedup 1.0000x reference)
//
#include <hip/hip_runtime.h>
#include <hip/hip_cooperative_groups.h>

namespace cg = cooperative_groups;

#define TT 128
#define HH 2048
#define VV 10000
#define VP 10112   // 79 * 128

typedef __attribute__((ext_vector_type(8))) short    s16x8;
typedef __attribute__((ext_vector_type(8))) _Float16 h16x8;
typedef __attribute__((ext_vector_type(4))) float    f32x4;

#define MFMA16(a,b,c) __builtin_amdgcn_mfma_f32_16x16x32_f16((a),(b),(c),0,0,0)

static __device__ __forceinline__ short f2h(float x){
  _Float16 h = (_Float16)x;
  return *(short*)&h;
}

// Swizzled fragment layout for an [N,K] matrix as MFMA B-operand (or [M,K] as A):
//   idx = ((nt*KC + kc)*64 + lane)*8 + j,  row = nt*16+(lane&15), k = kc*32+(lane>>4)*8+j
// -> a wave's fragment load is 64 lanes x 16B contiguous.

// ---------- W0 -> fp16: x-part (Wx, KC=64) and h-part (Wh, KC=64) ----------
__global__ __launch_bounds__(256) void k_prep_w0(
    const float* __restrict__ W0, short* __restrict__ Wx, short* __restrict__ Wh){
  int tid = blockIdx.x*256 + threadIdx.x;     // 2048*512 threads
  int row = tid >> 9;
  int c8  = (tid & 511) << 3;
  const float4* s = (const float4*)(W0 + (size_t)row*4096 + c8);
  float4 f0 = s[0], f1 = s[1];
  float v[8] = {f0.x,f0.y,f0.z,f0.w,f1.x,f1.y,f1.z,f1.w};
  short hs[8];
#pragma unroll
  for(int j=0;j<8;j++) hs[j]=f2h(v[j]);
  int isH = (c8 >= 2048);
  int k = c8 - (isH ? 2048 : 0);
  short* d = isH ? Wh : Wx;
  int nt = row>>4, kc = k>>5, ln = (row&15) | (((k>>3)&3)<<4);
  *(s16x8*)(d + ((size_t)(nt*64 + kc)*64 + ln)*8) = *(s16x8*)hs;
}

// ---------- W1 -> fp16, KC=128 ----------
__global__ __launch_bounds__(256) void k_prep_w1(
    const float* __restrict__ W1, short* __restrict__ W1h){
  int tid = blockIdx.x*256 + threadIdx.x;
  int row = tid >> 9;
  int c8  = (tid & 511) << 3;
  const float4* s = (const float4*)(W1 + (size_t)row*4096 + c8);
  float4 f0 = s[0], f1 = s[1];
  float v[8] = {f0.x,f0.y,f0.z,f0.w,f1.x,f1.y,f1.z,f1.w};
  short hs[8];
#pragma unroll
  for(int j=0;j<8;j++) hs[j]=f2h(v[j]);
  int nt = row>>4, kc = c8>>5, ln = (row&15) | (((c8>>3)&3)<<4);
  *(s16x8*)(W1h + ((size_t)(nt*128 + kc)*64 + ln)*8) = *(s16x8*)hs;
}

// ---------- Wout -> fp16, zero-padded to VP rows ----------
__global__ __launch_bounds__(256) void k_conv_wout(
    const float* __restrict__ Wout, short* __restrict__ Wo){
  int row = blockIdx.x;             // 0..VP-1
  int k = threadIdx.x << 3;
  short hs[8];
  if(row < VV){
    const float4* s = (const float4*)(Wout + (size_t)row*2048 + k);
    float4 f0 = s[0], f1 = s[1];
    float v[8] = {f0.x,f0.y,f0.z,f0.w,f1.x,f1.y,f1.z,f1.w};
#pragma unroll
    for(int j=0;j<8;j++) hs[j]=f2h(v[j]);
  } else {
#pragma unroll
    for(int j=0;j<8;j++) hs[j]=0;
  }
  int nt = row>>4, kc = k>>5, ln = (row&15) | (((k>>3)&3)<<4);
  *(s16x8*)(Wo + ((size_t)(nt*64 + kc)*64 + ln)*8) = *(s16x8*)hs;
}

// ---------- init h state: h0 -> parity0 buffer, h1 -> parity1 buffer ----------
__global__ __launch_bounds__(256) void k_init(
    const float* __restrict__ hid, short* __restrict__ h0a, short* __restrict__ h1b){
  int tid = blockIdx.x*256 + threadIdx.x;   // 32768
  int l = tid >> 14;
  int r = tid & 16383;
  int m = r >> 8;
  int k = (r & 255) << 3;
  const float* s = hid + ((size_t)l*64 + m)*HH + k;
  short hs[8];
#pragma unroll
  for(int j=0;j<8;j++) hs[j]=f2h(s[j]);
  short* d = l ? h1b : h0a;
  int mt = m>>4, kc = k>>5, ln = (m&15) | (((k>>3)&3)<<4);
  *(s16x8*)(d + ((size_t)(mt*64 + kc)*64 + ln)*8) = *(s16x8*)hs;
}

// ---------- gather emb rows -> fp16 A-swizzled [8192, 2048] ----------
__global__ __launch_bounds__(256) void k_gather(
    const int* __restrict__ toks, const float* __restrict__ emb, short* __restrict__ Aemb){
  int row = blockIdx.x;             // 8192 = t*64+b
  int k = threadIdx.x << 3;
  int tok = toks[row];
  const float4* s = (const float4*)(emb + (size_t)tok*2048 + k);
  float4 f0 = s[0], f1 = s[1];
  float v[8] = {f0.x,f0.y,f0.z,f0.w,f1.x,f1.y,f1.z,f1.w};
  short hs[8];
#pragma unroll
  for(int j=0;j<8;j++) hs[j]=f2h(v[j]);
  int mt = row>>4, kc = k>>5, ln = (row&15) | (((k>>3)&3)<<4);
  *(s16x8*)(Aemb + ((size_t)(mt*64 + kc)*64 + ln)*8) = *(s16x8*)hs;
}

// ---------- Phase A: P0 = Aemb @ Wx^T + b0  (fp16, 128-col tiles) ----------
__global__ __launch_bounds__(256) void k_gemmA(
    const short* __restrict__ Aemb, const short* __restrict__ Wx,
    const float* __restrict__ b0, float* __restrict__ P0){
  __shared__ short aS[2][2048];
  int bx = blockIdx.x, by = blockIdx.y;   // bx: 16 col-groups of 128; by: 128 row-groups of 64
  int tid = threadIdx.x, w = tid>>6, ln = tid&63;
  int nt0 = bx*8 + w*2;
  f32x4 z = {0,0,0,0};
  f32x4 acc[2][4];
#pragma unroll
  for(int u=0;u<2;u++)
#pragma unroll
    for(int mt=0;mt<4;mt++) acc[u][mt]=z;
  for(int kc=0;kc<64;kc++){
    int par = kc&1;
    s16x8 av = *(const s16x8*)(Aemb + ((size_t)((by*4+w)*64 + kc)*64 + ln)*8);
    *(s16x8*)&aS[par][tid*8] = av;
    __syncthreads();
    h16x8 bf0 = *(const h16x8*)(Wx + ((size_t)(nt0*64 + kc)*64 + ln)*8);
    h16x8 bf1 = *(const h16x8*)(Wx + ((size_t)((nt0+1)*64 + kc)*64 + ln)*8);
#pragma unroll
    for(int mt=0;mt<4;mt++){
      h16x8 ah = *(const h16x8*)&aS[par][(mt*64+ln)*8];
      acc[0][mt] = MFMA16(ah,bf0,acc[0][mt]);
      acc[1][mt] = MFMA16(ah,bf1,acc[1][mt]);
    }
  }
#pragma unroll
  for(int u=0;u<2;u++){
    int n = (nt0+u)*16 + (ln&15);
    float bias = b0[n];
    int r0 = (ln>>4)*4;
#pragma unroll
    for(int mt=0;mt<4;mt++)
#pragma unroll
      for(int r=0;r<4;r++){
        int m = by*64 + mt*16 + r0 + r;
        P0[(size_t)m*HH + n] = acc[u][mt][r] + bias;
      }
  }
}

// ---------- persistent cooperative recurrence ----------
// 256 blocks: bid<128 -> L1 tile nt=bid; bid>=128 -> L0 tile nt=bid-128.
// Phase p (0..128): L0 computes h0 step p (p<128); L1 computes h1 step p-1 (p>=1).
// h-state ping-pong: read buf[p&1], write buf[(p+1)&1]. Weights live in VGPRs.
__global__ __launch_bounds__(256,1) void k_recur(
    const short* __restrict__ Wh, const short* __restrict__ W1h,
    const float* __restrict__ P0, const float* __restrict__ b1v,
    short* h0a, short* h0b, short* h1a, short* h1b,
    short* __restrict__ H1s, float* outHid){
  __shared__ float red[4][64][16];
  cg::grid_group grid = cg::this_grid();
  int bid = blockIdx.x;
  bool isL1 = bid < 128;
  int nt = isL1 ? bid : (bid-128);
  int tid = threadIdx.x, w = tid>>6, ln = tid&63;
  f32x4 z = {0,0,0,0};

  h16x8 B[32];
  if(isL1){
#pragma unroll
    for(int i=0;i<32;i++)
      B[i] = *(const h16x8*)(W1h + ((size_t)(nt*128 + w*32 + i)*64 + ln)*8);
  } else {
#pragma unroll
    for(int i=0;i<16;i++)
      B[i] = *(const h16x8*)(Wh + ((size_t)(nt*64 + w*16 + i)*64 + ln)*8);
  }

  for(int p=0;p<=128;p++){
    const short* h0r = (p&1)? h0b : h0a;
    if(isL1){
      if(p>=1){
        const short* h1r = (p&1)? h1b : h1a;
        short* h1w = (p&1)? h1a : h1b;
        const short* aB = (w<2)? h0r : h1r;   // K = [h0_new | h1_old]
        int kbase = (w&1)*32;
        f32x4 acc[4] = {{0,0,0,0},{0,0,0,0},{0,0,0,0},{0,0,0,0}};
#pragma unroll
        for(int i=0;i<32;i++){
          int kcl = kbase + i;
#pragma unroll
          for(int mt=0;mt<4;mt++){
            h16x8 a = *(const h16x8*)(aB + ((size_t)(mt*64 + kcl)*64 + ln)*8);
            acc[mt] = MFMA16(a, B[i], acc[mt]);
          }
        }
#pragma unroll
        for(int mt=0;mt<4;mt++)
#pragma unroll
          for(int r=0;r<4;r++)
            red[w][mt*16 + (ln>>4)*4 + r][ln&15] = acc[mt][r];
        __syncthreads();
        int m = tid>>2, nl0 = (tid&3)*4;
        int t = p-1;
        short* H1t = H1s + (size_t)t*64*2048;
#pragma unroll
        for(int i=0;i<4;i++){
          int nl = nl0+i, n = nt*16 + nl;
          float s2 = red[0][m][nl]+red[1][m][nl]+red[2][m][nl]+red[3][m][nl];
          float val = tanhf(s2 + b1v[n]);
          short hb = f2h(val);
          int mtile = m>>4, kc2 = n>>5, ln2 = (m&15) | (((n>>3)&3)<<4), j = n&7;
          size_t idx = ((size_t)(mtile*64 + kc2)*64 + ln2)*8 + j;
          h1w[idx] = hb;
          H1t[idx] = hb;
          if(p==128) outHid[(size_t)(64+m)*HH + n] = val;
        }
      }
    } else {
      if(p<128){
        short* h0w = (p&1)? h0a : h0b;
        f32x4 acc[4] = {{0,0,0,0},{0,0,0,0},{0,0,0,0},{0,0,0,0}};
#pragma unroll
        for(int i=0;i<16;i++){
          int kc = w*16 + i;
#pragma unroll
          for(int mt=0;mt<4;mt++){
            h16x8 a = *(const h16x8*)(h0r + ((size_t)(mt*64 + kc)*64 + ln)*8);
            acc[mt] = MFMA16(a, B[i], acc[mt]);
          }
        }
#pragma unroll
        for(int mt=0;mt<4;mt++)
#pragma unroll
          for(int r=0;r<4;r++)
            red[w][mt*16 + (ln>>4)*4 + r][ln&15] = acc[mt][r];
        __syncthreads();
        int m = tid>>2, nl0 = (tid&3)*4;
#pragma unroll
        for(int i=0;i<4;i++){
          int nl = nl0+i, n = nt*16 + nl;
          float s2 = red[0][m][nl]+red[1][m][nl]+red[2][m][nl]+red[3][m][nl];
          float val = tanhf(s2 + P0[((size_t)p*64 + m)*HH + n]);
          short hb = f2h(val);
          int mtile = m>>4, kc2 = n>>5, ln2 = (m&15) | (((n>>3)&3)<<4), j = n&7;
          size_t idx = ((size_t)(mtile*64 + kc2)*64 + ln2)*8 + j;
          h0w[idx] = hb;
          if(p==127) outHid[(size_t)m*HH + n] = val;
        }
      }
    }
    __threadfence();
    grid.sync();
  }
}

// ---------- Phase C: logits = H1 @ Wout^T + bout  (fp16, 128-col tiles) ----------
__global__ __launch_bounds__(256) void k_gemmC(
    const short* __restrict__ H1s, const short* __restrict__ Wo,
    const float* __restrict__ bout, float* __restrict__ outp){
  __shared__ short aS[2][2048];
  int bx = blockIdx.x, by = blockIdx.y;   // bx: 79 col-groups of 128; by: 128 row-groups of 64
  int tid = threadIdx.x, w = tid>>6, ln = tid&63;
  int nt0 = bx*8 + w*2;
  f32x4 z = {0,0,0,0};
  f32x4 acc[2][4];
#pragma unroll
  for(int u=0;u<2;u++)
#pragma unroll
    for(int mt=0;mt<4;mt++) acc[u][mt]=z;
  for(int kc=0;kc<64;kc++){
    int par = kc&1;
    s16x8 av = *(const s16x8*)(H1s + ((size_t)((by*4+w)*64 + kc)*64 + ln)*8);
    *(s16x8*)&aS[par][tid*8] = av;
    __syncthreads();
    h16x8 bf0 = *(const h16x8*)(Wo + ((size_t)(nt0*64 + kc)*64 + ln)*8);
    h16x8 bf1 = *(const h16x8*)(Wo + ((size_t)((nt0+1)*64 + kc)*64 + ln)*8);
#pragma unroll
    for(int mt=0;mt<4;mt++){
      h16x8 ah = *(const h16x8*)&aS[par][(mt*64+ln)*8];
      acc[0][mt] = MFMA16(ah,bf0,acc[0][mt]);
      acc[1][mt] = MFMA16(ah,bf1,acc[1][mt]);
    }
  }
#pragma unroll
  for(int u=0;u<2;u++){
    int n = (nt0+u)*16 + (ln&15);
    if(n < VV){
      float bias = bout[n];
      int r0 = (ln>>4)*4;
#pragma unroll
      for(int mt=0;mt<4;mt++)
#pragma unroll
        for(int r=0;r<4;r++){
          int m = by*64 + mt*16 + r0 + r;
          outp[(size_t)m*VV + n] = acc[u][mt][r] + bias;
        }
    }
  }
}

extern "C" void kernel_launch(void* const* d_in, const int* in_sizes, int n_in,
                              void* d_out, int out_size, void* d_ws, size_t ws_size,
                              hipStream_t stream){
  const int*   toks = (const int*)d_in[0];
  const float* hid  = (const float*)d_in[1];
  const float* emb  = (const float*)d_in[2];
  const float* W0   = (const float*)d_in[3];
  const float* b0   = (const float*)d_in[4];
  const float* W1   = (const float*)d_in[5];
  const float* b1   = (const float*)d_in[6];
  const float* Wout = (const float*)d_in[7];
  const float* bout = (const float*)d_in[8];
  float* out = (float*)d_out;

  char* ws = (char*)d_ws;
  size_t off = 0;
  auto take = [&](size_t bytes)->void*{
    void* r = ws + off; off += (bytes + 255) & ~(size_t)255; return r; };

  short* Wx   = (short*)take((size_t)2048*2048*2);
  short* Wh   = (short*)take((size_t)2048*2048*2);
  short* W1h  = (short*)take((size_t)2048*4096*2);
  short* Wo   = (short*)take((size_t)VP*2048*2);
  short* Aemb = (short*)take((size_t)8192*2048*2);
  float* P0   = (float*)take((size_t)8192*2048*4);
  short* H1s  = (short*)take((size_t)8192*2048*2);
  short* h0a  = (short*)take((size_t)64*2048*2);
  short* h0b  = (short*)take((size_t)64*2048*2);
  short* h1a  = (short*)take((size_t)64*2048*2);
  short* h1b  = (short*)take((size_t)64*2048*2);
  float* outHid = out + (size_t)8192*VV;

  k_prep_w0<<<4096,256,0,stream>>>(W0, Wx, Wh);
  k_prep_w1<<<4096,256,0,stream>>>(W1, W1h);
  k_conv_wout<<<VP,256,0,stream>>>(Wout, Wo);
  k_init<<<128,256,0,stream>>>(hid, h0a, h1b);
  k_gather<<<8192,256,0,stream>>>(toks, emb, Aemb);
  k_gemmA<<<dim3(16,128),256,0,stream>>>(Aemb, Wx, b0, P0);

  void* args[] = {&Wh,&W1h,&P0,&b1,&h0a,&h0b,&h1a,&h1b,&H1s,&outHid};
  hipLaunchCooperativeKernel((const void*)k_recur, dim3(256), dim3(256),
                             args, 0, stream);

  k_gemmC<<<dim3(79,128),256,0,stream>>>(H1s, Wo, bout, out);
}